// Round 1
// baseline (427.699 us; speedup 1.0000x reference)
//
#include <hip/hip_runtime.h>
#include <hip/hip_bf16.h>
#include <stdint.h>

#define N_NODES 50000
#define N_EDGES 800000
#define IN_FEAT 256
#define OUT_FEAT 256
#define NUM_RELS 64
#define NUM_BASES 8
#define KTOT 2304           // 8*256 (bases) + 256 (self loop)
#define MP 50048            // 391 * 128, padded M for the GEMM
#define SCAN_BLKS 196       // ceil(50000/256)

typedef __attribute__((ext_vector_type(8))) __bf16 bf16x8;
typedef __attribute__((ext_vector_type(4))) float f32x4;

// ---- async global->LDS, 16B per lane. LDS dest must be wave-uniform base;
// HW writes base + lane*16. Casts go through integers to dodge addrspace-cast
// restrictions (low 32 bits of a generic LDS pointer are the LDS byte offset).
static __device__ __forceinline__ void gload_lds16(const void* g, void* l) {
  auto gp = (const __attribute__((address_space(1))) void*)(uintptr_t)g;
  auto lp = (__attribute__((address_space(3))) void*)(uint32_t)(uintptr_t)l;
  __builtin_amdgcn_global_load_lds(gp, lp, 16, 0, 0);
}

// ---------------- CSR build ----------------
__global__ void k_count(const int* __restrict__ dst, int* __restrict__ deg) {
  int e = blockIdx.x * 256 + threadIdx.x;
  atomicAdd(&deg[dst[e]], 1);
}

__global__ void k_scan1(const int* __restrict__ deg, int* __restrict__ offs,
                        int* __restrict__ bsum) {
  __shared__ int s[256];
  int t = threadIdx.x;
  int i = blockIdx.x * 256 + t;
  int v = (i < N_NODES) ? deg[i] : 0;
  s[t] = v;
  __syncthreads();
  for (int d = 1; d < 256; d <<= 1) {
    int y = (t >= d) ? s[t - d] : 0;
    __syncthreads();
    s[t] += y;
    __syncthreads();
  }
  if (i < N_NODES) offs[i] = s[t] - v;          // exclusive within block
  if (t == 255) bsum[blockIdx.x] = s[255];
}

__global__ void k_scan2(const int* __restrict__ bsum, int* __restrict__ bbase) {
  __shared__ int s[256];
  int t = threadIdx.x;
  int v = (t < SCAN_BLKS) ? bsum[t] : 0;
  s[t] = v;
  __syncthreads();
  for (int d = 1; d < 256; d <<= 1) {
    int y = (t >= d) ? s[t - d] : 0;
    __syncthreads();
    s[t] += y;
    __syncthreads();
  }
  if (t < SCAN_BLKS) bbase[t] = s[t] - v;       // exclusive block bases
}

__global__ void k_scan3(int* __restrict__ offs, const int* __restrict__ bbase,
                        int* __restrict__ fill) {
  int i = blockIdx.x * 256 + threadIdx.x;
  if (i < N_NODES) {
    int o = offs[i] + bbase[blockIdx.x];
    offs[i] = o;
    fill[i] = o;
  }
}

__global__ void k_scatter(const int* __restrict__ dst, int* __restrict__ fill,
                          int* __restrict__ eidx) {
  int e = blockIdx.x * 256 + threadIdx.x;
  int pos = atomicAdd(&fill[dst[e]], 1);
  eidx[pos] = e;
}

// ---------------- per-node aggregation: one wave per node ----------------
// lane owns features {lane, lane+64, lane+128, lane+192} x 8 bases (32 f32 regs).
// After k_scatter, fill[n] == end offset of node n's edge list.
__global__ void k_agg(const float* __restrict__ x, const float* __restrict__ norm,
                      const int* __restrict__ srcv, const int* __restrict__ ety,
                      const float* __restrict__ w_comp, const int* __restrict__ offs,
                      const int* __restrict__ fin, const int* __restrict__ eidx,
                      __bf16* __restrict__ A) {
  __shared__ float wc[NUM_RELS * NUM_BASES];   // 512 floats
  int t = threadIdx.x;
  wc[t] = w_comp[t];
  wc[t + 256] = w_comp[t + 256];
  __syncthreads();

  int wid = t >> 6, lane = t & 63;
  int node = blockIdx.x * 4 + wid;             // grid = 12500 -> exactly 50000

  float acc[NUM_BASES][4];
#pragma unroll
  for (int b = 0; b < NUM_BASES; ++b)
#pragma unroll
    for (int j = 0; j < 4; ++j) acc[b][j] = 0.f;

  int i0 = offs[node], i1 = fin[node];
  for (int i = i0; i < i1; ++i) {
    int e = eidx[i];
    int sv = srcv[e];
    float nm = norm[e];
    int et = ety[e];
    const float* xr = x + (size_t)sv * IN_FEAT + lane;
    float v0 = xr[0] * nm;
    float v1 = xr[64] * nm;
    float v2 = xr[128] * nm;
    float v3 = xr[192] * nm;
    const float* cw = &wc[et * NUM_BASES];
#pragma unroll
    for (int b = 0; b < NUM_BASES; ++b) {
      float c = cw[b];
      acc[b][0] += v0 * c;
      acc[b][1] += v1 * c;
      acc[b][2] += v2 * c;
      acc[b][3] += v3 * c;
    }
  }

  __bf16* Ar = A + (size_t)node * KTOT;
#pragma unroll
  for (int b = 0; b < NUM_BASES; ++b)
#pragma unroll
    for (int j = 0; j < 4; ++j)
      Ar[b * 256 + j * 64 + lane] = (__bf16)acc[b][j];

  const float* xn = x + (size_t)node * IN_FEAT;
#pragma unroll
  for (int j = 0; j < 4; ++j)
    Ar[2048 + j * 64 + lane] = (__bf16)xn[j * 64 + lane];
}

// ---------------- weight prep: Wt[o][r] = Wcat[r][o] in bf16 ----------------
__global__ void k_prepw(const float* __restrict__ weight, const float* __restrict__ loop_w,
                        __bf16* __restrict__ Wt) {
  int o = blockIdx.x;        // output col 0..255
  int t = threadIdx.x;
#pragma unroll
  for (int c = 0; c < 9; ++c) {
    int r = c * 256 + t;     // 0..2303
    float v = (r < 2048) ? weight[(size_t)r * 256 + o]
                         : loop_w[(size_t)(r - 2048) * 256 + o];
    Wt[(size_t)o * KTOT + r] = (__bf16)v;
  }
}

// ---------------- GEMM: out[M][256] = A[M][2304] @ Wt^T + bias, relu --------
// m97 structure: 128x128 tile, BK=32, 4 waves (2x2), global_load_lds staging.
__global__ __launch_bounds__(256, 2) void k_gemm(const __bf16* __restrict__ A,
                                                 const __bf16* __restrict__ Wt,
                                                 const float* __restrict__ bias,
                                                 float* __restrict__ out) {
  __shared__ __align__(16) __bf16 sA[128 * 32];
  __shared__ __align__(16) __bf16 sB[128 * 32];

  int t = threadIdx.x;
  int wid = t >> 6, lane = t & 63;
  int bx = blockIdx.x;
  int tm = bx >> 1, tn = bx & 1;               // 391 x 2 tiles
  int wr = wid >> 1, wc = wid & 1;             // wave -> 64x64 quadrant
  int rfw = __builtin_amdgcn_readfirstlane(wid);

  f32x4 acc[4][4];
#pragma unroll
  for (int m = 0; m < 4; ++m)
#pragma unroll
    for (int n = 0; n < 4; ++n) acc[m][n] = f32x4{0.f, 0.f, 0.f, 0.f};

  int frow = lane & 15;
  int fkb = (lane >> 4) * 16;                  // byte offset of k-slice (8 bf16)

  for (int kt = 0; kt < KTOT / 32; ++kt) {
    int k0 = kt * 32;
    // stage: A tile 128x32 bf16 (8KB) + B tile 128x32 (8KB); 512 chunks each
#pragma unroll
    for (int it = 0; it < 2; ++it) {
      int c = it * 256 + t;                    // chunk id; row = c>>2, kpart = c&3
      const __bf16* ga = A + (size_t)(tm * 128 + (c >> 2)) * KTOT + k0 + (c & 3) * 8;
      char* la = (char*)sA + (it * 256 + rfw * 64) * 16;
      gload_lds16(ga, la);
      const __bf16* gb = Wt + (size_t)(tn * 128 + (c >> 2)) * KTOT + k0 + (c & 3) * 8;
      char* lb = (char*)sB + (it * 256 + rfw * 64) * 16;
      gload_lds16(gb, lb);
    }
    __syncthreads();

    bf16x8 af[4], bfr[4];
#pragma unroll
    for (int m = 0; m < 4; ++m) {
      int row = wr * 64 + m * 16 + frow;
      af[m] = *(const bf16x8*)((const char*)sA + row * 64 + fkb);
    }
#pragma unroll
    for (int n = 0; n < 4; ++n) {
      int row = wc * 64 + n * 16 + frow;
      bfr[n] = *(const bf16x8*)((const char*)sB + row * 64 + fkb);
    }
#pragma unroll
    for (int m = 0; m < 4; ++m)
#pragma unroll
      for (int n = 0; n < 4; ++n)
        acc[m][n] = __builtin_amdgcn_mfma_f32_16x16x32_bf16(af[m], bfr[n], acc[m][n], 0, 0, 0);
    __syncthreads();
  }

  // epilogue: C/D layout col = lane&15, row = (lane>>4)*4 + r  [m89]
  int r0 = (lane >> 4) * 4;
  int c0 = lane & 15;
#pragma unroll
  for (int m = 0; m < 4; ++m) {
    int rowb = tm * 128 + wr * 64 + m * 16 + r0;
#pragma unroll
    for (int n = 0; n < 4; ++n) {
      int col = tn * 128 + wc * 64 + n * 16 + c0;
      float bv = bias[col];
#pragma unroll
      for (int r = 0; r < 4; ++r) {
        int row = rowb + r;
        if (row < N_NODES) {
          float v = acc[m][n][r] + bv;
          out[(size_t)row * OUT_FEAT + col] = v > 0.f ? v : 0.f;
        }
      }
    }
  }
}

extern "C" void kernel_launch(void* const* d_in, const int* in_sizes, int n_in,
                              void* d_out, int out_size, void* d_ws, size_t ws_size,
                              hipStream_t stream) {
  const float* x      = (const float*)d_in[0];
  const int*   src    = (const int*)d_in[1];
  const int*   dst    = (const int*)d_in[2];
  const int*   ety    = (const int*)d_in[3];
  const float* norm   = (const float*)d_in[4];
  const float* weight = (const float*)d_in[5];
  const float* w_comp = (const float*)d_in[6];
  const float* h_bias = (const float*)d_in[7];
  const float* loop_w = (const float*)d_in[8];
  float* out = (float*)d_out;

  char* ws = (char*)d_ws;
  __bf16* A  = (__bf16*)ws;                                 // MP*KTOT bf16 = 230.6MB
  size_t off = (size_t)MP * KTOT * 2;
  __bf16* Wt = (__bf16*)(ws + off);                         // 256*KTOT bf16 = 1.18MB
  off += (size_t)256 * KTOT * 2;
  int* eidx = (int*)(ws + off);                             // 3.2MB
  off += (size_t)N_EDGES * 4;
  int* deg   = (int*)(ws + off);
  int* offs  = deg + N_NODES;
  int* fill  = offs + N_NODES;
  int* bsum  = fill + N_NODES;
  int* bbase = bsum + 256;

  hipMemsetAsync(deg, 0, N_NODES * sizeof(int), stream);
  k_count<<<N_EDGES / 256, 256, 0, stream>>>(dst, deg);
  k_scan1<<<SCAN_BLKS, 256, 0, stream>>>(deg, offs, bsum);
  k_scan2<<<1, 256, 0, stream>>>(bsum, bbase);
  k_scan3<<<SCAN_BLKS, 256, 0, stream>>>(offs, bbase, fill);
  k_scatter<<<N_EDGES / 256, 256, 0, stream>>>(dst, fill, eidx);
  k_agg<<<N_NODES / 4, 256, 0, stream>>>(x, norm, src, ety, w_comp, offs, fill, eidx, A);
  k_prepw<<<256, 256, 0, stream>>>(weight, loop_w, Wt);
  k_gemm<<<391 * 2, 256, 0, stream>>>(A, Wt, h_bias, out);
}

// Round 2
// 342.275 us; speedup vs baseline: 1.2496x; 1.2496x over previous
//
#include <hip/hip_runtime.h>
#include <hip/hip_bf16.h>
#include <stdint.h>

#define N_NODES 50000
#define N_EDGES 800000
#define IN_FEAT 256
#define OUT_FEAT 256
#define NUM_RELS 64
#define NUM_BASES 8
#define KTOT 2304           // 8*256 (bases) + 256 (self loop) -- Wt stride
#define KAGG 2048           // A matrix K (bases only; self-loop read from xb)
#define MP 50048            // 782 * 64, padded M
#define SCAN_BLKS 196       // ceil(50000/256)

typedef __attribute__((ext_vector_type(8))) __bf16 bf16x8;
typedef __attribute__((ext_vector_type(4))) __bf16 bf16x4;
typedef __attribute__((ext_vector_type(4))) float f32x4;
typedef __attribute__((ext_vector_type(2))) float f32x2;

static __device__ __forceinline__ void gload_lds16(const void* g, void* l) {
  auto gp = (const __attribute__((address_space(1))) void*)(uintptr_t)g;
  auto lp = (__attribute__((address_space(3))) void*)(uint32_t)(uintptr_t)l;
  __builtin_amdgcn_global_load_lds(gp, lp, 16, 0, 0);
}

// ---------------- x -> bf16 ----------------
__global__ void k_prex(const float* __restrict__ x, __bf16* __restrict__ xb) {
  int i = blockIdx.x * 256 + threadIdx.x;        // one thread = 8 elems; grid 6250
  const float4* xp = (const float4*)x;
  float4 u = xp[i * 2], v = xp[i * 2 + 1];
  bf16x8 o;
  o[0] = (__bf16)u.x; o[1] = (__bf16)u.y; o[2] = (__bf16)u.z; o[3] = (__bf16)u.w;
  o[4] = (__bf16)v.x; o[5] = (__bf16)v.y; o[6] = (__bf16)v.z; o[7] = (__bf16)v.w;
  *(bf16x8*)(xb + (size_t)i * 8) = o;
}

// ---------------- CSR build ----------------
__global__ void k_count(const int* __restrict__ dst, int* __restrict__ deg) {
  int e = blockIdx.x * 256 + threadIdx.x;
  atomicAdd(&deg[dst[e]], 1);
}

__global__ void k_scan1(const int* __restrict__ deg, int* __restrict__ offs,
                        int* __restrict__ bsum) {
  __shared__ int s[256];
  int t = threadIdx.x;
  int i = blockIdx.x * 256 + t;
  int v = (i < N_NODES) ? deg[i] : 0;
  s[t] = v;
  __syncthreads();
  for (int d = 1; d < 256; d <<= 1) {
    int y = (t >= d) ? s[t - d] : 0;
    __syncthreads();
    s[t] += y;
    __syncthreads();
  }
  if (i < N_NODES) offs[i] = s[t] - v;
  if (t == 255) bsum[blockIdx.x] = s[255];
}

__global__ void k_scan2(const int* __restrict__ bsum, int* __restrict__ bbase) {
  __shared__ int s[256];
  int t = threadIdx.x;
  int v = (t < SCAN_BLKS) ? bsum[t] : 0;
  s[t] = v;
  __syncthreads();
  for (int d = 1; d < 256; d <<= 1) {
    int y = (t >= d) ? s[t - d] : 0;
    __syncthreads();
    s[t] += y;
    __syncthreads();
  }
  if (t < SCAN_BLKS) bbase[t] = s[t] - v;
}

__global__ void k_scan3(int* __restrict__ offs, const int* __restrict__ bbase,
                        int* __restrict__ fill) {
  int i = blockIdx.x * 256 + threadIdx.x;
  if (i < N_NODES) {
    int o = offs[i] + bbase[blockIdx.x];
    offs[i] = o;
    fill[i] = o;
  }
}

// scatter packed edge records {src|ety<<16, norm} into CSR order
__global__ void k_scatter(const int* __restrict__ dst, const int* __restrict__ srcv,
                          const int* __restrict__ ety, const float* __restrict__ norm,
                          int* __restrict__ fill, uint2* __restrict__ erec) {
  int e = blockIdx.x * 256 + threadIdx.x;
  int pos = atomicAdd(&fill[dst[e]], 1);
  erec[pos] = make_uint2((unsigned)srcv[e] | ((unsigned)ety[e] << 16),
                         __float_as_uint(norm[e]));
}

// ---------------- per-node aggregation: one wave per node ----------------
// lane owns 4 CONSECUTIVE features [lane*4 .. lane*4+3] x 8 bases.
__global__ __launch_bounds__(256) void k_agg(
    const __bf16* __restrict__ xb, const float* __restrict__ w_comp,
    const int* __restrict__ offs, const int* __restrict__ fin,
    const uint2* __restrict__ erec, __bf16* __restrict__ A) {
  __shared__ float wc[NUM_RELS * NUM_BASES];   // 512 floats
  int t = threadIdx.x;
  wc[t] = w_comp[t];
  wc[t + 256] = w_comp[t + 256];
  __syncthreads();

  int wid = t >> 6, lane = t & 63;
  int node = blockIdx.x * 4 + wid;             // grid 12500 -> exactly 50000

  f32x2 acc[NUM_BASES][2];
#pragma unroll
  for (int b = 0; b < NUM_BASES; ++b) {
    acc[b][0] = f32x2{0.f, 0.f};
    acc[b][1] = f32x2{0.f, 0.f};
  }

  int i0 = offs[node];
  int cnt = fin[node] - i0;
  const uint2* rp = erec + i0;
  int lo4 = lane * 4;

  int i = 0;
  for (; i + 4 <= cnt; i += 4) {
    uint2 r[4];
#pragma unroll
    for (int j = 0; j < 4; ++j) r[j] = rp[i + j];
    uint2 xv[4];
#pragma unroll
    for (int j = 0; j < 4; ++j) {
      int sv = r[j].x & 0xffff;
      xv[j] = *(const uint2*)(xb + (size_t)sv * IN_FEAT + lo4);
    }
#pragma unroll
    for (int j = 0; j < 4; ++j) {
      int et = r[j].x >> 16;
      float nm = __uint_as_float(r[j].y);
      float a0 = __uint_as_float(xv[j].x << 16);
      float a1 = __uint_as_float(xv[j].x & 0xffff0000u);
      float a2 = __uint_as_float(xv[j].y << 16);
      float a3 = __uint_as_float(xv[j].y & 0xffff0000u);
      f32x2 v0 = {a0 * nm, a1 * nm};
      f32x2 v1 = {a2 * nm, a3 * nm};
      f32x4 cl = *(const f32x4*)&wc[et * 8];
      f32x4 ch = *(const f32x4*)&wc[et * 8 + 4];
#pragma unroll
      for (int b = 0; b < 4; ++b) {
        acc[b][0] += v0 * cl[b];
        acc[b][1] += v1 * cl[b];
        acc[b + 4][0] += v0 * ch[b];
        acc[b + 4][1] += v1 * ch[b];
      }
    }
  }
  for (; i < cnt; ++i) {
    uint2 r = rp[i];
    int sv = r.x & 0xffff;
    int et = r.x >> 16;
    float nm = __uint_as_float(r.y);
    uint2 xv = *(const uint2*)(xb + (size_t)sv * IN_FEAT + lo4);
    float a0 = __uint_as_float(xv.x << 16);
    float a1 = __uint_as_float(xv.x & 0xffff0000u);
    float a2 = __uint_as_float(xv.y << 16);
    float a3 = __uint_as_float(xv.y & 0xffff0000u);
    f32x2 v0 = {a0 * nm, a1 * nm};
    f32x2 v1 = {a2 * nm, a3 * nm};
    f32x4 cl = *(const f32x4*)&wc[et * 8];
    f32x4 ch = *(const f32x4*)&wc[et * 8 + 4];
#pragma unroll
    for (int b = 0; b < 4; ++b) {
      acc[b][0] += v0 * cl[b];
      acc[b][1] += v1 * cl[b];
      acc[b + 4][0] += v0 * ch[b];
      acc[b + 4][1] += v1 * ch[b];
    }
  }

  __bf16* Ar = A + (size_t)node * KAGG + lo4;
#pragma unroll
  for (int b = 0; b < NUM_BASES; ++b) {
    bf16x4 o;
    o[0] = (__bf16)acc[b][0][0];
    o[1] = (__bf16)acc[b][0][1];
    o[2] = (__bf16)acc[b][1][0];
    o[3] = (__bf16)acc[b][1][1];
    *(bf16x4*)(Ar + b * 256) = o;
  }
}

// ---------------- weight prep: Wt[o][r] = Wcat[r][o] in bf16 ----------------
__global__ void k_prepw(const float* __restrict__ weight, const float* __restrict__ loop_w,
                        __bf16* __restrict__ Wt) {
  int o = blockIdx.x;
  int t = threadIdx.x;
#pragma unroll
  for (int c = 0; c < 9; ++c) {
    int r = c * 256 + t;
    float v = (r < 2048) ? weight[(size_t)r * 256 + o]
                         : loop_w[(size_t)(r - 2048) * 256 + o];
    Wt[(size_t)o * KTOT + r] = (__bf16)v;
  }
}

// ---------------- GEMM: out[M][256] = [A | xb] @ Wt^T + bias, relu ----------
// 64x256 tile, BK=32, 4 waves (each 64 rows x 64-col quadrant), grid 782.
__global__ __launch_bounds__(256, 2) void k_gemm(const __bf16* __restrict__ A,
                                                 const __bf16* __restrict__ xb,
                                                 const __bf16* __restrict__ Wt,
                                                 const float* __restrict__ bias,
                                                 float* __restrict__ out) {
  __shared__ __align__(16) __bf16 sA[64 * 32];    // 4KB
  __shared__ __align__(16) __bf16 sB[256 * 32];   // 16KB

  int t = threadIdx.x;
  int wid = t >> 6, lane = t & 63;
  int tm = blockIdx.x;
  int rfw = __builtin_amdgcn_readfirstlane(wid);

  f32x4 acc[4][4];
#pragma unroll
  for (int m = 0; m < 4; ++m)
#pragma unroll
    for (int n = 0; n < 4; ++n) acc[m][n] = f32x4{0.f, 0.f, 0.f, 0.f};

  int frow = lane & 15;
  int fkb = (lane >> 4) * 16;

  for (int kt = 0; kt < 72; ++kt) {
    int k0 = kt * 32;
    // stage A tile 64x32 (4KB): chunk c = t; row=c>>2, kpart=c&3
    int arow = tm * 64 + (t >> 2);
    const __bf16* ga = (kt < 64)
        ? A + (size_t)arow * KAGG + k0 + (t & 3) * 8
        : xb + (size_t)arow * IN_FEAT + (k0 - KAGG) + (t & 3) * 8;
    gload_lds16(ga, (char*)sA + rfw * 1024);
    // stage B tile 256x32 (16KB): 4 chunks/thread
#pragma unroll
    for (int it = 0; it < 4; ++it) {
      int c = it * 256 + t;
      const __bf16* gb = Wt + (size_t)(c >> 2) * KTOT + k0 + (c & 3) * 8;
      gload_lds16(gb, (char*)sB + (it * 256 + rfw * 64) * 16);
    }
    __syncthreads();

    bf16x8 af[4], bfr[4];
#pragma unroll
    for (int m = 0; m < 4; ++m)
      af[m] = *(const bf16x8*)((const char*)sA + (m * 16 + frow) * 64 + fkb);
#pragma unroll
    for (int n = 0; n < 4; ++n)
      bfr[n] = *(const bf16x8*)((const char*)sB + (wid * 64 + n * 16 + frow) * 64 + fkb);
#pragma unroll
    for (int m = 0; m < 4; ++m)
#pragma unroll
      for (int n = 0; n < 4; ++n)
        acc[m][n] = __builtin_amdgcn_mfma_f32_16x16x32_bf16(af[m], bfr[n], acc[m][n], 0, 0, 0);
    __syncthreads();
  }

  // epilogue: col = lane&15, row = (lane>>4)*4 + r  [m89]
  int r0 = (lane >> 4) * 4;
  int c0 = lane & 15;
#pragma unroll
  for (int m = 0; m < 4; ++m) {
    int rowb = tm * 64 + m * 16 + r0;
#pragma unroll
    for (int n = 0; n < 4; ++n) {
      int col = wid * 64 + n * 16 + c0;
      float bv = bias[col];
#pragma unroll
      for (int r = 0; r < 4; ++r) {
        int row = rowb + r;
        if (row < N_NODES) {
          float v = acc[m][n][r] + bv;
          out[(size_t)row * OUT_FEAT + col] = v > 0.f ? v : 0.f;
        }
      }
    }
  }
}

extern "C" void kernel_launch(void* const* d_in, const int* in_sizes, int n_in,
                              void* d_out, int out_size, void* d_ws, size_t ws_size,
                              hipStream_t stream) {
  const float* x      = (const float*)d_in[0];
  const int*   src    = (const int*)d_in[1];
  const int*   dst    = (const int*)d_in[2];
  const int*   ety    = (const int*)d_in[3];
  const float* norm   = (const float*)d_in[4];
  const float* weight = (const float*)d_in[5];
  const float* w_comp = (const float*)d_in[6];
  const float* h_bias = (const float*)d_in[7];
  const float* loop_w = (const float*)d_in[8];
  float* out = (float*)d_out;

  char* ws = (char*)d_ws;
  __bf16* A  = (__bf16*)ws;                                 // MP*2048*2 = 205.0MB
  size_t off = (size_t)MP * KAGG * 2;
  __bf16* xb = (__bf16*)(ws + off);                         // MP*256*2 = 25.6MB
  off += (size_t)MP * IN_FEAT * 2;
  __bf16* Wt = (__bf16*)(ws + off);                         // 1.18MB
  off += (size_t)256 * KTOT * 2;
  uint2* erec = (uint2*)(ws + off);                         // 6.4MB
  off += (size_t)N_EDGES * 8;
  int* deg   = (int*)(ws + off);
  int* offs  = deg + N_NODES;
  int* fill  = offs + N_NODES;
  int* bsum  = fill + N_NODES;
  int* bbase = bsum + 256;

  hipMemsetAsync(deg, 0, N_NODES * sizeof(int), stream);
  k_prex<<<(N_NODES * IN_FEAT / 8) / 256, 256, 0, stream>>>(x, xb);
  k_count<<<N_EDGES / 256, 256, 0, stream>>>(dst, deg);
  k_scan1<<<SCAN_BLKS, 256, 0, stream>>>(deg, offs, bsum);
  k_scan2<<<1, 256, 0, stream>>>(bsum, bbase);
  k_scan3<<<SCAN_BLKS, 256, 0, stream>>>(offs, bbase, fill);
  k_scatter<<<N_EDGES / 256, 256, 0, stream>>>(dst, src, ety, norm, fill, erec);
  k_agg<<<N_NODES / 4, 256, 0, stream>>>(xb, w_comp, offs, fill, erec, A);
  k_prepw<<<256, 256, 0, stream>>>(weight, loop_w, Wt);
  k_gemm<<<MP / 64, 256, 0, stream>>>(A, xb, Wt, h_bias, out);
}